// Round 13
// baseline (532.346 us; speedup 1.0000x reference)
//
#include <hip/hip_runtime.h>
#include <hip/hip_bf16.h>

#define N_DIM 128
#define NHEADS 4
#define HEAD_DIM 32

typedef unsigned short bf16_t;
typedef short bf16x8 __attribute__((ext_vector_type(8)));
typedef float f32x4 __attribute__((ext_vector_type(4)));

__device__ __forceinline__ float lof(unsigned int u) {
    union { unsigned int i; float f; } x; x.i = u << 16; return x.f;
}
__device__ __forceinline__ float hif(unsigned int u) {
    union { unsigned int i; float f; } x; x.i = u & 0xffff0000u; return x.f;
}

__device__ __forceinline__ bf16_t f32_to_bf16(float f) {
    union { float f; unsigned int i; } x;
    x.f = f;
    unsigned int r = x.i + 0x7FFFu + ((x.i >> 16) & 1u);  // RNE
    return (bf16_t)(r >> 16);
}

__device__ __forceinline__ unsigned int pack2(float a, float b) {
    return (unsigned int)f32_to_bf16(a) | ((unsigned int)f32_to_bf16(b) << 16);
}

// padded LDS stride for the 32x128 bf16 A-tile: 136 elems = 272 B
#define LDA_STRIDE 136

// ---------------------------------------------------------------------------
// K0: transpose W's to bf16.  Wt[384][128] = {Wq^T,Wk^T,Wv^T}, Wot = Wo^T.
// ---------------------------------------------------------------------------
__global__ __launch_bounds__(128) void transpose_w_kernel(
    const float* __restrict__ Wq, const float* __restrict__ Wk,
    const float* __restrict__ Wv, const float* __restrict__ Wo,
    bf16_t* __restrict__ Wt, bf16_t* __restrict__ Wot)
{
    const int n = blockIdx.x;    // 0..511
    const int k = threadIdx.x;   // 0..127
    const float* W; bf16_t* dst; int nl;
    if (n < 128)      { W = Wq; nl = n;       dst = Wt  + n * 128; }
    else if (n < 256) { W = Wk; nl = n - 128; dst = Wt  + n * 128; }
    else if (n < 384) { W = Wv; nl = n - 256; dst = Wt  + n * 128; }
    else              { W = Wo; nl = n - 384; dst = Wot + (n - 384) * 128; }
    dst[k] = f32_to_bf16(W[k * 128 + nl]);
}

// ---------------------------------------------------------------------------
// K1 (MFMA, swapped operands): q/k/v projections, bf16 out.  (measured-good)
// ---------------------------------------------------------------------------
__global__ __launch_bounds__(256) void qkv_mfma_kernel(
    const float* __restrict__ nodes,
    const bf16_t* __restrict__ Wt,
    const float* __restrict__ bq, const float* __restrict__ bk,
    const float* __restrict__ bv,
    bf16_t* __restrict__ qb, bf16_t* __restrict__ kb, bf16_t* __restrict__ vb,
    int N)
{
    __shared__ bf16_t lds_a[32 * LDA_STRIDE];
    const int tid = threadIdx.x;
    const int m0 = blockIdx.x * 32;

#pragma unroll
    for (int i = 0; i < 4; ++i) {
        const int f = tid + 256 * i;
        const int row = f >> 5, c4 = f & 31;
        const int g = m0 + row;
        float4 v = make_float4(0.f, 0.f, 0.f, 0.f);
        if (g < N) v = ((const float4*)nodes)[(size_t)g * 32 + c4];
        ushort4 u;
        u.x = f32_to_bf16(v.x); u.y = f32_to_bf16(v.y);
        u.z = f32_to_bf16(v.z); u.w = f32_to_bf16(v.w);
        *(ushort4*)(lds_a + row * LDA_STRIDE + c4 * 4) = u;
    }
    __syncthreads();

    const int w  = tid >> 6;
    const int l  = tid & 63;
    const int lr = l & 15;
    const int lg = l >> 4;

    bf16x8 a[2][4];
#pragma unroll
    for (int mt = 0; mt < 2; ++mt)
#pragma unroll
        for (int kt = 0; kt < 4; ++kt)
            a[mt][kt] = *(const bf16x8*)(lds_a + (mt * 16 + lr) * LDA_STRIDE
                                         + kt * 32 + lg * 8);

#pragma unroll
    for (int ni = 0; ni < 6; ++ni) {
        const int nt = w * 6 + ni;          // 0..23
        f32x4 acc0 = {0.f, 0.f, 0.f, 0.f};
        f32x4 acc1 = {0.f, 0.f, 0.f, 0.f};
#pragma unroll
        for (int kt = 0; kt < 4; ++kt) {
            const bf16x8 b = *(const bf16x8*)(Wt + (size_t)(nt * 16 + lr) * 128
                                              + kt * 32 + lg * 8);
            acc0 = __builtin_amdgcn_mfma_f32_16x16x32_bf16(b, a[0][kt], acc0, 0, 0, 0);
            acc1 = __builtin_amdgcn_mfma_f32_16x16x32_bf16(b, a[1][kt], acc1, 0, 0, 0);
        }
        const int fb = nt * 16 + lg * 4;
        bf16_t* dst; int cl; const float* bias;
        if (nt < 8)       { dst = qb; cl = fb;       bias = bq; }
        else if (nt < 16) { dst = kb; cl = fb - 128; bias = bk; }
        else              { dst = vb; cl = fb - 256; bias = bv; }
        const float4 b4 = *(const float4*)(bias + cl);

        uint2 p0, p1;
        p0.x = pack2(acc0[0] + b4.x, acc0[1] + b4.y);
        p0.y = pack2(acc0[2] + b4.z, acc0[3] + b4.w);
        p1.x = pack2(acc1[0] + b4.x, acc1[1] + b4.y);
        p1.y = pack2(acc1[2] + b4.z, acc1[3] + b4.w);

        const int r0 = m0 + lr;
        const int r1 = m0 + 16 + lr;
        if (r0 < N) *(uint2*)(dst + (size_t)r0 * 128 + cl) = p0;
        if (r1 < N) *(uint2*)(dst + (size_t)r1 * 128 + cl) = p1;
    }
}

// ---------------------------------------------------------------------------
// CSR build: histogram -> fused single-block scan -> scatter
// ---------------------------------------------------------------------------
__global__ __launch_bounds__(256) void hist_kernel(
    const int* __restrict__ receivers, int* __restrict__ cnt, int E)
{
    const int i = blockIdx.x * 256 + threadIdx.x;
    if (i < E) atomicAdd(&cnt[receivers[i]], 1);
}

// ONE block (1024 thr): exclusive scan of cnt[0..N) -> starts & cursor;
// starts[N] = total.  Each thread owns a contiguous chunk.
__global__ __launch_bounds__(1024) void scan_all_kernel(
    const int* __restrict__ cnt, int* __restrict__ starts,
    int* __restrict__ cursor, int N)
{
    __shared__ int wsum[16];
    __shared__ int woff[16];
    const int t = threadIdx.x;
    const int wid = t >> 6, lane = t & 63;
    const int chunk = (N + 1023) >> 10;
    const int b0 = t * chunk;
    const int b1 = min(b0 + chunk, N);

    int s = 0;
    for (int i = b0; i < b1; ++i) s += cnt[i];
    const int my = s;

    // inclusive wave scan
    for (int off = 1; off < 64; off <<= 1) {
        int x = __shfl_up(s, off);
        if (lane >= off) s += x;
    }
    if (lane == 63) wsum[wid] = s;
    __syncthreads();
    if (t == 0) {
        int run = 0;
        for (int w = 0; w < 16; ++w) { woff[w] = run; run += wsum[w]; }
        starts[N] = run;   // grand total = E
    }
    __syncthreads();

    int run = s - my + woff[wid];   // exclusive prefix of my chunk
    for (int i = b0; i < b1; ++i) {
        starts[i] = run;
        cursor[i] = run;
        run += cnt[i];
    }
}

__global__ __launch_bounds__(256) void scatter_kernel(
    const int* __restrict__ senders, const int* __restrict__ receivers,
    int* __restrict__ cursor, int* __restrict__ elist, int E)
{
    const int i = blockIdx.x * 256 + threadIdx.x;
    if (i < E) {
        const int pos = atomicAdd(&cursor[receivers[i]], 1);
        elist[pos] = senders[i];
    }
}

// ---------------------------------------------------------------------------
// K2 (CSR aggregate, 16-lane groups): 4 receivers per wave, so every wave
// instruction (incl. the 4 v_exp) serves 4 edges at once.  Per group the
// uint4/lane loads cover one 256B row contiguously -> same transaction count
// per edge as the wave-coalesced version.
// ---------------------------------------------------------------------------
__global__ __launch_bounds__(256) void agg16_kernel(
    const int* __restrict__ starts, const int* __restrict__ elist,
    const bf16_t* __restrict__ qb, const bf16_t* __restrict__ kb,
    const bf16_t* __restrict__ vb,
    bf16_t* __restrict__ agg_b, int N)
{
    const int r = blockIdx.x * 16 + (threadIdx.x >> 4);
    const int l16 = threadIdx.x & 15;
    if (r >= N) return;

    const int sbase = threadIdx.x & 0x30;   // group base lane within wave
    const int h = l16 >> 2;                 // this lane's head
    const int start = starts[r];
    const int end   = starts[r + 1];

    const uint4 ku = *(const uint4*)(kb + (size_t)r * N_DIM + l16 * 8);
    const float k0 = lof(ku.x), k1 = hif(ku.x), k2 = lof(ku.y), k3 = hif(ku.y);
    const float k4 = lof(ku.z), k5 = hif(ku.z), k6 = lof(ku.w), k7 = hif(ku.w);

    float a0 = 0.f, a1 = 0.f, a2 = 0.f, a3 = 0.f;
    float a4 = 0.f, a5 = 0.f, a6 = 0.f, a7 = 0.f;
    const float scale = 0.17677669529663687f;  // 1/sqrt(32)

    for (int j = start; j < end; ++j) {
        const int s = elist[j];
        const uint4 qu = *(const uint4*)(qb + (size_t)s * N_DIM + l16 * 8);

        float p;
        p = lof(qu.x) * k0;
        p = fmaf(hif(qu.x), k1, p);
        p = fmaf(lof(qu.y), k2, p);
        p = fmaf(hif(qu.y), k3, p);
        p = fmaf(lof(qu.z), k4, p);
        p = fmaf(hif(qu.z), k5, p);
        p = fmaf(lof(qu.w), k6, p);
        p = fmaf(hif(qu.w), k7, p);

        // reduce over the 4-lane quad (one head per quad)
        p += __shfl_xor(p, 1);
        p += __shfl_xor(p, 2);

        // head sums live at quad bases sbase + {0,4,8,12}
        const float s0 = __shfl(p, sbase + 0)  * scale;
        const float s1 = __shfl(p, sbase + 4)  * scale;
        const float s2 = __shfl(p, sbase + 8)  * scale;
        const float s3 = __shfl(p, sbase + 12) * scale;

        const float m = fmaxf(fmaxf(s0, s1), fmaxf(s2, s3));
        const float e0 = __expf(s0 - m);
        const float e1 = __expf(s1 - m);
        const float e2 = __expf(s2 - m);
        const float e3 = __expf(s3 - m);
        const float inv = 1.0f / (e0 + e1 + e2 + e3);
        const float w = (h == 0 ? e0 : h == 1 ? e1 : h == 2 ? e2 : e3) * inv;

        const uint4 vu = *(const uint4*)(vb + (size_t)s * N_DIM + l16 * 8);
        a0 = fmaf(lof(vu.x), w, a0);
        a1 = fmaf(hif(vu.x), w, a1);
        a2 = fmaf(lof(vu.y), w, a2);
        a3 = fmaf(hif(vu.y), w, a3);
        a4 = fmaf(lof(vu.z), w, a4);
        a5 = fmaf(hif(vu.z), w, a5);
        a6 = fmaf(lof(vu.w), w, a6);
        a7 = fmaf(hif(vu.w), w, a7);
    }

    uint4 o;
    o.x = pack2(a0, a1);
    o.y = pack2(a2, a3);
    o.z = pack2(a4, a5);
    o.w = pack2(a6, a7);
    *(uint4*)(agg_b + (size_t)r * N_DIM + l16 * 8) = o;
}

// ---------------------------------------------------------------------------
// (kept for quick revert; unused) K2 round-9 wave-per-receiver aggregate
// ---------------------------------------------------------------------------
__global__ __launch_bounds__(256) void agg_kernel(
    const int* __restrict__ starts, const int* __restrict__ elist,
    const bf16_t* __restrict__ qb, const bf16_t* __restrict__ kb,
    const bf16_t* __restrict__ vb,
    bf16_t* __restrict__ agg_b, int N)
{
    const int r = blockIdx.x * 4 + (threadIdx.x >> 6);
    const int lane = threadIdx.x & 63;
    if (r >= N) return;

    const int start = starts[r];
    const int end   = starts[r + 1];
    const int c = lane * 2;

    const unsigned int ku = *(const unsigned int*)(kb + (size_t)r * N_DIM + c);
    const float kx = lof(ku), ky = hif(ku);

    float ax = 0.f, ay = 0.f;
    const float scale = 0.17677669529663687f;
    const int h = lane >> 4;

    for (int j0 = start; j0 < end; j0 += 64) {
        const int ids = (j0 + lane < end) ? elist[j0 + lane] : 0;
        const int jm = min(64, end - j0);
        for (int j = 0; j < jm; ++j) {
            const int s = __shfl(ids, j);
            const unsigned int qu =
                *(const unsigned int*)(qb + (size_t)s * N_DIM + c);
            const unsigned int vu =
                *(const unsigned int*)(vb + (size_t)s * N_DIM + c);
            float p = lof(qu) * kx + hif(qu) * ky;
            p += __shfl_xor(p, 1);
            p += __shfl_xor(p, 2);
            p += __shfl_xor(p, 4);
            p += __shfl_xor(p, 8);
            const float s0 = __shfl(p, 0)  * scale;
            const float s1 = __shfl(p, 16) * scale;
            const float s2 = __shfl(p, 32) * scale;
            const float s3 = __shfl(p, 48) * scale;
            const float m = fmaxf(fmaxf(s0, s1), fmaxf(s2, s3));
            const float e0 = __expf(s0 - m);
            const float e1 = __expf(s1 - m);
            const float e2 = __expf(s2 - m);
            const float e3 = __expf(s3 - m);
            const float inv = 1.0f / (e0 + e1 + e2 + e3);
            const float aw = (h == 0 ? e0 : h == 1 ? e1 : h == 2 ? e2 : e3) * inv;
            ax = fmaf(lof(vu), aw, ax);
            ay = fmaf(hif(vu), aw, ay);
        }
    }
    *(unsigned int*)(agg_b + (size_t)r * N_DIM + c) = pack2(ax, ay);
}

// ---------------------------------------------------------------------------
// K3 (MFMA, swapped operands): out = agg_b @ Wo + bo + nodes.  (measured-good)
// ---------------------------------------------------------------------------
__global__ __launch_bounds__(256) void out_mfma_b_kernel(
    const float* __restrict__ nodes,
    const bf16_t* __restrict__ agg_b,
    const bf16_t* __restrict__ Wot,
    const float* __restrict__ bo,
    float* __restrict__ out, int N)
{
    __shared__ bf16_t lds_a[32 * LDA_STRIDE];
    const int tid = threadIdx.x;
    const int m0 = blockIdx.x * 32;

#pragma unroll
    for (int i = 0; i < 4; ++i) {
        const int f = tid + 256 * i;
        const int row = f >> 5, c4 = f & 31;
        const int g = m0 + row;
        ushort4 u = make_ushort4(0, 0, 0, 0);
        if (g < N) u = ((const ushort4*)(agg_b + (size_t)g * N_DIM))[c4];
        *(ushort4*)(lds_a + row * LDA_STRIDE + c4 * 4) = u;
    }
    __syncthreads();

    const int w  = tid >> 6;
    const int l  = tid & 63;
    const int lr = l & 15;
    const int lg = l >> 4;

    bf16x8 a[2][4];
#pragma unroll
    for (int mt = 0; mt < 2; ++mt)
#pragma unroll
        for (int kt = 0; kt < 4; ++kt)
            a[mt][kt] = *(const bf16x8*)(lds_a + (mt * 16 + lr) * LDA_STRIDE
                                         + kt * 32 + lg * 8);

#pragma unroll
    for (int ni = 0; ni < 2; ++ni) {
        const int nt = w * 2 + ni;
        f32x4 acc0 = {0.f, 0.f, 0.f, 0.f};
        f32x4 acc1 = {0.f, 0.f, 0.f, 0.f};
#pragma unroll
        for (int kt = 0; kt < 4; ++kt) {
            const bf16x8 b = *(const bf16x8*)(Wot + (size_t)(nt * 16 + lr) * 128
                                              + kt * 32 + lg * 8);
            acc0 = __builtin_amdgcn_mfma_f32_16x16x32_bf16(b, a[0][kt], acc0, 0, 0, 0);
            acc1 = __builtin_amdgcn_mfma_f32_16x16x32_bf16(b, a[1][kt], acc1, 0, 0, 0);
        }
        const int fb = nt * 16 + lg * 4;
        const float4 b4 = *(const float4*)(bo + fb);

        const int r0 = m0 + lr;
        const int r1 = m0 + 16 + lr;
        if (r0 < N) {
            const float4 nd = *(const float4*)(nodes + (size_t)r0 * 128 + fb);
            float4 res;
            res.x = acc0[0] + b4.x + nd.x;
            res.y = acc0[1] + b4.y + nd.y;
            res.z = acc0[2] + b4.z + nd.z;
            res.w = acc0[3] + b4.w + nd.w;
            *(float4*)(out + (size_t)r0 * 128 + fb) = res;
        }
        if (r1 < N) {
            const float4 nd = *(const float4*)(nodes + (size_t)r1 * 128 + fb);
            float4 res;
            res.x = acc1[0] + b4.x + nd.x;
            res.y = acc1[1] + b4.y + nd.y;
            res.z = acc1[2] + b4.z + nd.z;
            res.w = acc1[3] + b4.w + nd.w;
            *(float4*)(out + (size_t)r1 * 128 + fb) = res;
        }
    }
}

// ---------------------------------------------------------------------------
// Fallback kernels (measured-correct mid path, used only if ws too small)
// ---------------------------------------------------------------------------
__global__ __launch_bounds__(256) void edge_kernel(
    const int* __restrict__ senders, const int* __restrict__ receivers,
    const bf16_t* __restrict__ qb, const bf16_t* __restrict__ kb,
    const bf16_t* __restrict__ vb,
    float* __restrict__ agg, int E)
{
    const int wid = threadIdx.x >> 6;
    const int lane = threadIdx.x & 63;
    const int e = blockIdx.x * 4 + wid;
    if (e >= E) return;

    const int s = senders[e];
    const int r = receivers[e];

    const int c = lane * 2;
    const unsigned int qu = *(const unsigned int*)(qb + (size_t)s * N_DIM + c);
    const unsigned int ku = *(const unsigned int*)(kb + (size_t)r * N_DIM + c);
    const unsigned int vu = *(const unsigned int*)(vb + (size_t)s * N_DIM + c);

    float p = lof(qu) * lof(ku) + hif(qu) * hif(ku);
    p += __shfl_xor(p, 1);
    p += __shfl_xor(p, 2);
    p += __shfl_xor(p, 4);
    p += __shfl_xor(p, 8);

    const float scale = 0.17677669529663687f;
    const float s0 = __shfl(p, 0)  * scale;
    const float s1 = __shfl(p, 16) * scale;
    const float s2 = __shfl(p, 32) * scale;
    const float s3 = __shfl(p, 48) * scale;

    const float m = fmaxf(fmaxf(s0, s1), fmaxf(s2, s3));
    const float e0 = __expf(s0 - m);
    const float e1 = __expf(s1 - m);
    const float e2 = __expf(s2 - m);
    const float e3 = __expf(s3 - m);
    const float inv = 1.0f / (e0 + e1 + e2 + e3);

    const int h = lane >> 4;
    const float aw = (h == 0 ? e0 : h == 1 ? e1 : h == 2 ? e2 : e3) * inv;

    float* dst = agg + (size_t)r * N_DIM + c;
    atomicAdd(dst, lof(vu) * aw);
    atomicAdd(dst + 1, hif(vu) * aw);
}

__global__ __launch_bounds__(256) void out_mfma_kernel(
    const float* __restrict__ nodes,
    const bf16_t* __restrict__ Wot,
    const float* __restrict__ bo,
    float* __restrict__ out, int N)
{
    __shared__ bf16_t lds_a[32 * LDA_STRIDE];
    const int tid = threadIdx.x;
    const int m0 = blockIdx.x * 32;

#pragma unroll
    for (int i = 0; i < 4; ++i) {
        const int f = tid + 256 * i;
        const int row = f >> 5, c4 = f & 31;
        const int g = m0 + row;
        float4 v = make_float4(0.f, 0.f, 0.f, 0.f);
        if (g < N) v = ((const float4*)out)[(size_t)g * 32 + c4];
        ushort4 u;
        u.x = f32_to_bf16(v.x); u.y = f32_to_bf16(v.y);
        u.z = f32_to_bf16(v.z); u.w = f32_to_bf16(v.w);
        *(ushort4*)(lds_a + row * LDA_STRIDE + c4 * 4) = u;
    }
    __syncthreads();

    const int w  = tid >> 6;
    const int l  = tid & 63;
    const int lr = l & 15;
    const int lg = l >> 4;

    bf16x8 a[2][4];
#pragma unroll
    for (int mt = 0; mt < 2; ++mt)
#pragma unroll
        for (int kt = 0; kt < 4; ++kt)
            a[mt][kt] = *(const bf16x8*)(lds_a + (mt * 16 + lr) * LDA_STRIDE
                                         + kt * 32 + lg * 8);

#pragma unroll
    for (int ni = 0; ni < 2; ++ni) {
        const int nt = w * 2 + ni;
        const int col = nt * 16 + lr;
        f32x4 acc0 = {0.f, 0.f, 0.f, 0.f};
        f32x4 acc1 = {0.f, 0.f, 0.f, 0.f};
#pragma unroll
        for (int kt = 0; kt < 4; ++kt) {
            const bf16x8 b = *(const bf16x8*)(Wot + (size_t)col * 128
                                              + kt * 32 + lg * 8);
            acc0 = __builtin_amdgcn_mfma_f32_16x16x32_bf16(a[0][kt], b, acc0, 0, 0, 0);
            acc1 = __builtin_amdgcn_mfma_f32_16x16x32_bf16(a[1][kt], b, acc1, 0, 0, 0);
        }
        const float bb = bo[col];
#pragma unroll
        for (int j = 0; j < 4; ++j) {
            const int r0 = m0 + lg * 4 + j;
            if (r0 < N)
                out[(size_t)r0 * 128 + col] =
                    acc0[j] + bb + nodes[(size_t)r0 * 128 + col];
            const int r1 = m0 + 16 + lg * 4 + j;
            if (r1 < N)
                out[(size_t)r1 * 128 + col] =
                    acc1[j] + bb + nodes[(size_t)r1 * 128 + col];
        }
    }
}

// ---------------------------------------------------------------------------
extern "C" void kernel_launch(void* const* d_in, const int* in_sizes, int n_in,
                              void* d_out, int out_size, void* d_ws, size_t ws_size,
                              hipStream_t stream)
{
    const float* nodes   = (const float*)d_in[0];
    const int* senders   = (const int*)d_in[1];
    const int* receivers = (const int*)d_in[2];
    const float* Wq = (const float*)d_in[3];
    const float* bq = (const float*)d_in[4];
    const float* Wk = (const float*)d_in[5];
    const float* bk = (const float*)d_in[6];
    const float* Wv = (const float*)d_in[7];
    const float* bv = (const float*)d_in[8];
    const float* Wo = (const float*)d_in[9];
    const float* bo = (const float*)d_in[10];

    const int N = in_sizes[0] / N_DIM;   // 100000
    const int E = in_sizes[1];           // 600000

    float* out = (float*)d_out;
    char* ws = (char*)d_ws;

    const size_t row_bytes = (size_t)N * N_DIM * sizeof(bf16_t);
    size_t off = 0;
    bf16_t* qb    = (bf16_t*)(ws + off); off += row_bytes;
    bf16_t* kb    = (bf16_t*)(ws + off); off += row_bytes;
    bf16_t* vb    = (bf16_t*)(ws + off); off += row_bytes;
    bf16_t* Wt    = (bf16_t*)(ws + off); off += 384 * 128 * sizeof(bf16_t);
    bf16_t* Wot   = (bf16_t*)(ws + off); off += 128 * 128 * sizeof(bf16_t);
    bf16_t* agg_b = (bf16_t*)(ws + off); off += row_bytes;
    int* cnt      = (int*)(ws + off);    off += (size_t)N * 4;
    int* starts   = (int*)(ws + off);    off += (size_t)(N + 1) * 4;
    int* cursor   = (int*)(ws + off);    off += (size_t)N * 4;
    int* elist    = (int*)(ws + off);    off += (size_t)E * 4;
    const size_t need_csr = off;
    const size_t need_mid = 3 * row_bytes + (384 + 128) * 128 * sizeof(bf16_t);

    if (ws_size >= need_csr) {
        transpose_w_kernel<<<512, 128, 0, stream>>>(Wq, Wk, Wv, Wo, Wt, Wot);
        qkv_mfma_kernel<<<(N + 31) / 32, 256, 0, stream>>>(
            nodes, Wt, bq, bk, bv, qb, kb, vb, N);

        hipMemsetAsync(cnt, 0, (size_t)N * 4, stream);
        hist_kernel<<<(E + 255) / 256, 256, 0, stream>>>(receivers, cnt, E);
        scan_all_kernel<<<1, 1024, 0, stream>>>(cnt, starts, cursor, N);
        scatter_kernel<<<(E + 255) / 256, 256, 0, stream>>>(
            senders, receivers, cursor, elist, E);

        agg16_kernel<<<(N + 15) / 16, 256, 0, stream>>>(
            starts, elist, qb, kb, vb, agg_b, N);

        out_mfma_b_kernel<<<(N + 31) / 32, 256, 0, stream>>>(
            nodes, agg_b, Wot, bo, out, N);
    } else if (ws_size >= need_mid) {
        hipMemsetAsync(d_out, 0, (size_t)N * N_DIM * sizeof(float), stream);
        transpose_w_kernel<<<512, 128, 0, stream>>>(Wq, Wk, Wv, Wo, Wt, Wot);
        qkv_mfma_kernel<<<(N + 31) / 32, 256, 0, stream>>>(
            nodes, Wt, bq, bk, bv, qb, kb, vb, N);
        edge_kernel<<<(E + 3) / 4, 256, 0, stream>>>(
            senders, receivers, qb, kb, vb, out, E);
        out_mfma_kernel<<<(N + 31) / 32, 256, 0, stream>>>(
            nodes, Wot, bo, out, N);
    }
}